// Round 1
// baseline (716.256 us; speedup 1.0000x reference)
//
#include <hip/hip_runtime.h>

#define N_SUM 2048
#define N_MAXS 64
#define M_IN 16
#define HIDD 128
#define OUT_D 64
#define NEDGE 16384
#define ROWS (N_SUM * N_MAXS)   // 131072

// ---------------- CSR build ----------------
__global__ __launch_bounds__(256) void zero_ints(int* p, int n) {
    int i = blockIdx.x * 256 + threadIdx.x;
    if (i < n) p[i] = 0;
}

__global__ __launch_bounds__(256) void count_deg(const int* __restrict__ dst, int* __restrict__ deg) {
    int e = blockIdx.x * 256 + threadIdx.x;
    if (e < NEDGE) atomicAdd(&deg[dst[e]], 1);
}

// 2048-element exclusive scan, single block of 256 threads (8 elems/thread)
__global__ __launch_bounds__(256) void scan_deg(const int* __restrict__ deg, int* __restrict__ row_ptr) {
    __shared__ int csum[256];
    int t = threadIdx.x;
    int loc[8];
    int s = 0;
#pragma unroll
    for (int q = 0; q < 8; q++) { loc[q] = s; s += deg[t * 8 + q]; }
    csum[t] = s;
    __syncthreads();
    for (int off = 1; off < 256; off <<= 1) {
        int v = (t >= off) ? csum[t - off] : 0;
        __syncthreads();
        csum[t] += v;
        __syncthreads();
    }
    int base = (t == 0) ? 0 : csum[t - 1];
#pragma unroll
    for (int q = 0; q < 8; q++) row_ptr[t * 8 + q] = base + loc[q];
    if (t == 255) row_ptr[2048] = csum[255];
}

__global__ __launch_bounds__(256) void fill_csr(const int* __restrict__ src, const int* __restrict__ dst,
                                                const int* __restrict__ row_ptr, int* __restrict__ cursor,
                                                int* __restrict__ col) {
    int e = blockIdx.x * 256 + threadIdx.x;
    if (e < NEDGE) {
        int d = dst[e];
        int pos = atomicAdd(&cursor[d], 1);
        col[row_ptr[d] + pos] = src[e];
    }
}

// ---------------- fused gather + matmul1 + BN partial stats ----------------
// Block = one node (64 rows). Gathers Z=(1+eps)X + sum_{in-edges} X[src] into LDS,
// computes H = Z@W1 + b1 (64 x 128), writes H, writes per-block per-feature sum/sumsq.
template <int D_IN>
__global__ __launch_bounds__(256) void gin_mm1(const float* __restrict__ X, const float* __restrict__ W1,
                                               const float* __restrict__ b1, const float* __restrict__ eps, int l,
                                               const int* __restrict__ row_ptr, const int* __restrict__ col,
                                               float* __restrict__ H, float* __restrict__ partial) {
    constexpr int SLAB = N_MAXS * D_IN;        // floats per node slab
    constexpr int NF4 = SLAB / 4 / 256;        // float4 per thread (8 for 128, 1 for 16)
    constexpr int PAD = D_IN + 4;              // LDS row stride (bank-conflict pad)
    constexpr int F4R = D_IN / 4;              // float4 per row
    constexpr int KC = (D_IN >= 32) ? 32 : D_IN;
    constexpr int NKB = D_IN / KC;

    __shared__ float Zs[N_MAXS * PAD];
    __shared__ float Wc[KC * HIDD];
    __shared__ float red[16 * HIDD];

    int tid = threadIdx.x;
    int n = blockIdx.x;

    // ---- gather phase: Z slab in registers -> LDS ----
    float ev = 1.0f + eps[l];
    float4 acc[NF4];
    const float4* Xn = (const float4*)(X + (size_t)n * SLAB);
#pragma unroll
    for (int q = 0; q < NF4; q++) {
        float4 v = Xn[tid + q * 256];
        acc[q].x = v.x * ev; acc[q].y = v.y * ev; acc[q].z = v.z * ev; acc[q].w = v.w * ev;
    }
    int e0 = row_ptr[n], e1 = row_ptr[n + 1];
    for (int j = e0; j < e1; j++) {
        const float4* Xs = (const float4*)(X + (size_t)col[j] * SLAB);
#pragma unroll
        for (int q = 0; q < NF4; q++) {
            float4 v = Xs[tid + q * 256];
            acc[q].x += v.x; acc[q].y += v.y; acc[q].z += v.z; acc[q].w += v.w;
        }
    }
#pragma unroll
    for (int q = 0; q < NF4; q++) {
        int f = tid + q * 256;
        int r = f / F4R, kc = f % F4R;
        *(float4*)&Zs[r * PAD + kc * 4] = acc[q];
    }

    // ---- matmul phase: 64 x D_IN @ D_IN x 128, thread tile 4 rows x 8 cols ----
    int rg = tid >> 4, cg = tid & 15;
    float accm[4][8];
#pragma unroll
    for (int i = 0; i < 4; i++)
#pragma unroll
        for (int j = 0; j < 8; j++) accm[i][j] = b1[cg * 8 + j];

    for (int kb = 0; kb < NKB; kb++) {
        __syncthreads();  // Zs ready (kb=0) / previous Wc readers done
        {
            const float4* wsrc = (const float4*)(W1 + kb * KC * HIDD);
#pragma unroll
            for (int q = 0; q < KC * HIDD / 1024; q++) ((float4*)Wc)[tid + q * 256] = wsrc[tid + q * 256];
        }
        __syncthreads();
#pragma unroll
        for (int k4 = 0; k4 < KC / 4; k4++) {
            float av[4][4];
#pragma unroll
            for (int i = 0; i < 4; i++) {
                float4 t = *(const float4*)&Zs[(rg * 4 + i) * PAD + kb * KC + k4 * 4];
                av[i][0] = t.x; av[i][1] = t.y; av[i][2] = t.z; av[i][3] = t.w;
            }
#pragma unroll
            for (int kk = 0; kk < 4; kk++) {
                float4 wlo = *(const float4*)&Wc[(k4 * 4 + kk) * HIDD + cg * 8];
                float4 whi = *(const float4*)&Wc[(k4 * 4 + kk) * HIDD + cg * 8 + 4];
                float wv[8] = {wlo.x, wlo.y, wlo.z, wlo.w, whi.x, whi.y, whi.z, whi.w};
#pragma unroll
                for (int i = 0; i < 4; i++)
#pragma unroll
                    for (int j = 0; j < 8; j++) accm[i][j] = fmaf(av[i][kk], wv[j], accm[i][j]);
            }
        }
    }

    // ---- write H ----
    float* Hrow = H + (size_t)n * N_MAXS * HIDD;
#pragma unroll
    for (int i = 0; i < 4; i++) {
        float4 lo = {accm[i][0], accm[i][1], accm[i][2], accm[i][3]};
        float4 hi = {accm[i][4], accm[i][5], accm[i][6], accm[i][7]};
        *(float4*)&Hrow[(rg * 4 + i) * HIDD + cg * 8] = lo;
        *(float4*)&Hrow[(rg * 4 + i) * HIDD + cg * 8 + 4] = hi;
    }

    // ---- BN partial stats: sum then sumsq over this block's 64 rows ----
#pragma unroll
    for (int j = 0; j < 8; j++) {
        float s = accm[0][j] + accm[1][j] + accm[2][j] + accm[3][j];
        red[rg * HIDD + cg * 8 + j] = s;
    }
    __syncthreads();
    if (tid < HIDD) {
        float t = 0.f;
#pragma unroll
        for (int g = 0; g < 16; g++) t += red[g * HIDD + tid];
        partial[(size_t)blockIdx.x * 256 + tid] = t;
    }
    __syncthreads();
#pragma unroll
    for (int j = 0; j < 8; j++) {
        float s = accm[0][j] * accm[0][j] + accm[1][j] * accm[1][j] + accm[2][j] * accm[2][j] +
                  accm[3][j] * accm[3][j];
        red[rg * HIDD + cg * 8 + j] = s;
    }
    __syncthreads();
    if (tid < HIDD) {
        float t = 0.f;
#pragma unroll
        for (int g = 0; g < 16; g++) t += red[g * HIDD + tid];
        partial[(size_t)blockIdx.x * 256 + HIDD + tid] = t;
    }
}

// ---------------- BN stats reduce -> per-feature scale/shift ----------------
__global__ __launch_bounds__(256) void bn_stats(const float* __restrict__ partial, const float* __restrict__ gamma,
                                                const float* __restrict__ beta, float* __restrict__ scsh) {
    __shared__ float rs[256], rs2[256];
    int c = blockIdx.x, t = threadIdx.x;
    float s = 0.f, s2 = 0.f;
    for (int b = t; b < 2048; b += 256) {
        s += partial[(size_t)b * 256 + c];
        s2 += partial[(size_t)b * 256 + HIDD + c];
    }
    rs[t] = s; rs2[t] = s2;
    __syncthreads();
    for (int off = 128; off > 0; off >>= 1) {
        if (t < off) { rs[t] += rs[t + off]; rs2[t] += rs2[t + off]; }
        __syncthreads();
    }
    if (t == 0) {
        float mean = rs[0] / (float)ROWS;
        float var = rs2[0] / (float)ROWS - mean * mean;
        float sc = gamma[c] * rsqrtf(var + 1e-5f);
        scsh[c] = sc;
        scsh[HIDD + c] = beta[c] - mean * sc;
    }
}

// ---------------- matmul2: relu(H*scale+shift) @ W2 + b2 ----------------
// LAST=true additionally fuses PE[n][c] = sum_r mask[n][r] * X_out[n][r][c] -> d_out
template <int D_OUT, bool LAST>
__global__ __launch_bounds__(256) void gin_mm2(const float* __restrict__ H, const float* __restrict__ W2,
                                               const float* __restrict__ b2, const float* __restrict__ scsh,
                                               const float* __restrict__ mask, float* __restrict__ out) {
    constexpr int PAD = HIDD + 4;
    constexpr int TN = D_OUT / 16;  // cols per thread: 8 or 4
    __shared__ float Hs[N_MAXS * PAD];
    __shared__ float Wc[32 * D_OUT];
    __shared__ float red[LAST ? 16 * OUT_D : 1];

    int tid = threadIdx.x;
    int n = blockIdx.x;

    // ---- load H rows with BN + ReLU applied ----
    const float4* H4 = (const float4*)(H + (size_t)n * N_MAXS * HIDD);
    const float4* sc4 = (const float4*)scsh;
#pragma unroll
    for (int q = 0; q < 8; q++) {
        int f = tid + q * 256;
        int r = f >> 5, c4 = f & 31;
        float4 h = H4[f];
        float4 sc = sc4[c4], sh = sc4[32 + c4];
        float4 v;
        v.x = fmaxf(fmaf(h.x, sc.x, sh.x), 0.f);
        v.y = fmaxf(fmaf(h.y, sc.y, sh.y), 0.f);
        v.z = fmaxf(fmaf(h.z, sc.z, sh.z), 0.f);
        v.w = fmaxf(fmaf(h.w, sc.w, sh.w), 0.f);
        *(float4*)&Hs[r * PAD + c4 * 4] = v;
    }

    int rg = tid >> 4, cg = tid & 15;
    float accm[4][TN];
#pragma unroll
    for (int i = 0; i < 4; i++)
#pragma unroll
        for (int j = 0; j < TN; j++) accm[i][j] = b2[cg * TN + j];

    for (int kb = 0; kb < 4; kb++) {  // 128 / 32
        __syncthreads();
        {
            const float4* wsrc = (const float4*)(W2 + kb * 32 * D_OUT);
#pragma unroll
            for (int q = 0; q < 32 * D_OUT / 1024; q++) ((float4*)Wc)[tid + q * 256] = wsrc[tid + q * 256];
        }
        __syncthreads();
#pragma unroll
        for (int k4 = 0; k4 < 8; k4++) {
            float av[4][4];
#pragma unroll
            for (int i = 0; i < 4; i++) {
                float4 t = *(const float4*)&Hs[(rg * 4 + i) * PAD + kb * 32 + k4 * 4];
                av[i][0] = t.x; av[i][1] = t.y; av[i][2] = t.z; av[i][3] = t.w;
            }
#pragma unroll
            for (int kk = 0; kk < 4; kk++) {
                float wv[TN];
#pragma unroll
                for (int j4 = 0; j4 < TN / 4; j4++) {
                    float4 w = *(const float4*)&Wc[(k4 * 4 + kk) * D_OUT + cg * TN + j4 * 4];
                    wv[j4 * 4 + 0] = w.x; wv[j4 * 4 + 1] = w.y; wv[j4 * 4 + 2] = w.z; wv[j4 * 4 + 3] = w.w;
                }
#pragma unroll
                for (int i = 0; i < 4; i++)
#pragma unroll
                    for (int j = 0; j < TN; j++) accm[i][j] = fmaf(av[i][kk], wv[j], accm[i][j]);
            }
        }
    }

    if (!LAST) {
        float* Orow = out + (size_t)n * N_MAXS * D_OUT;
#pragma unroll
        for (int i = 0; i < 4; i++) {
#pragma unroll
            for (int j4 = 0; j4 < TN / 4; j4++) {
                float4 v = {accm[i][j4 * 4 + 0], accm[i][j4 * 4 + 1], accm[i][j4 * 4 + 2], accm[i][j4 * 4 + 3]};
                *(float4*)&Orow[(rg * 4 + i) * D_OUT + cg * TN + j4 * 4] = v;
            }
        }
    } else {
        float mk[4];
#pragma unroll
        for (int i = 0; i < 4; i++) mk[i] = mask[n * N_MAXS + rg * 4 + i];
#pragma unroll
        for (int j = 0; j < TN; j++) {
            float pe = accm[0][j] * mk[0] + accm[1][j] * mk[1] + accm[2][j] * mk[2] + accm[3][j] * mk[3];
            red[rg * OUT_D + cg * TN + j] = pe;
        }
        __syncthreads();
        if (tid < OUT_D) {
            float t = 0.f;
#pragma unroll
            for (int g = 0; g < 16; g++) t += red[g * OUT_D + tid];
            out[(size_t)n * OUT_D + tid] = t;
        }
    }
}

// ---------------- host launch ----------------
extern "C" void kernel_launch(void* const* d_in, const int* in_sizes, int n_in, void* d_out, int out_size,
                              void* d_ws, size_t ws_size, hipStream_t stream) {
    const float* W    = (const float*)d_in[0];
    const float* mask = (const float*)d_in[1];
    const int* src    = (const int*)d_in[2];
    const int* dst    = (const int*)d_in[3];
    const float* eps  = (const float*)d_in[4];
    const float* W1f  = (const float*)d_in[5];
    const float* b1f  = (const float*)d_in[6];
    const float* W1r  = (const float*)d_in[7];
    const float* b1r  = (const float*)d_in[8];
    const float* gam  = (const float*)d_in[9];
    const float* bet  = (const float*)d_in[10];
    const float* W2m  = (const float*)d_in[11];
    const float* b2m  = (const float*)d_in[12];
    const float* W2l  = (const float*)d_in[13];
    const float* b2l  = (const float*)d_in[14];
    float* out = (float*)d_out;

    // workspace layout (floats)
    float* Xbuf    = (float*)d_ws;           // 2048*64*128 = 16,777,216 floats
    float* Hbuf    = Xbuf + 16777216;        // 16,777,216 floats
    float* partial = Hbuf + 16777216;        // 2048*256 floats
    float* scsh    = partial + 2048 * 256;   // 256 floats
    int* ideg      = (int*)(scsh + 256);     // 2048
    int* icur      = ideg + 2048;            // 2048 (contiguous with ideg for zeroing)
    int* irp       = icur + 2048;            // 2049
    int* icol      = irp + 2052;             // 16384 (small alignment gap after 2049)

    // CSR build (src/dst constant across layers; rebuilt every call, ~10us)
    zero_ints<<<16, 256, 0, stream>>>(ideg, 4096);
    count_deg<<<NEDGE / 256, 256, 0, stream>>>(dst, ideg);
    scan_deg<<<1, 256, 0, stream>>>(ideg, irp);
    fill_csr<<<NEDGE / 256, 256, 0, stream>>>(src, dst, irp, icur, icol);

    for (int l = 0; l < 4; l++) {
        const float* Xin = (l == 0) ? W : Xbuf;
        const float* W1  = (l == 0) ? W1f : (W1r + (size_t)(l - 1) * HIDD * HIDD);
        const float* b1  = (l == 0) ? b1f : (b1r + (size_t)(l - 1) * HIDD);
        if (l == 0)
            gin_mm1<16><<<N_SUM, 256, 0, stream>>>(Xin, W1, b1, eps, l, irp, icol, Hbuf, partial);
        else
            gin_mm1<128><<<N_SUM, 256, 0, stream>>>(Xin, W1, b1, eps, l, irp, icol, Hbuf, partial);

        bn_stats<<<HIDD, 256, 0, stream>>>(partial, gam + l * HIDD, bet + l * HIDD, scsh);

        if (l < 3)
            gin_mm2<128, false><<<N_SUM, 256, 0, stream>>>(Hbuf, W2m + (size_t)l * HIDD * HIDD, b2m + l * HIDD,
                                                           scsh, nullptr, Xbuf);
        else
            gin_mm2<64, true><<<N_SUM, 256, 0, stream>>>(Hbuf, W2l, b2l, scsh, mask, out);
    }
}

// Round 2
// 349.755 us; speedup vs baseline: 2.0479x; 2.0479x over previous
//
#include <hip/hip_runtime.h>

#define N_SUM 2048
#define N_MAXS 64
#define M_IN 16
#define HIDD 128
#define OUT_D 64
#define NEDGE 16384
#define ROWS (N_SUM * N_MAXS)   // 131072

typedef short short8 __attribute__((ext_vector_type(8)));
typedef float floatx4 __attribute__((ext_vector_type(4)));
typedef unsigned short ushort_t;

__device__ __forceinline__ ushort_t f2bf(float f) {
    unsigned u = __builtin_bit_cast(unsigned, f);
    u += 0x7fffu + ((u >> 16) & 1u);   // RNE
    return (ushort_t)(u >> 16);
}
__device__ __forceinline__ float bf2f(ushort_t h) {
    return __builtin_bit_cast(float, (unsigned)h << 16);
}
__device__ __forceinline__ void unpack8(uint4 v, float* f) {
    f[0] = bf2f(v.x & 0xffff); f[1] = bf2f(v.x >> 16);
    f[2] = bf2f(v.y & 0xffff); f[3] = bf2f(v.y >> 16);
    f[4] = bf2f(v.z & 0xffff); f[5] = bf2f(v.z >> 16);
    f[6] = bf2f(v.w & 0xffff); f[7] = bf2f(v.w >> 16);
}
__device__ __forceinline__ uint4 pack8(const float* f) {
    uint4 v;
    v.x = f2bf(f[0]) | ((unsigned)f2bf(f[1]) << 16);
    v.y = f2bf(f[2]) | ((unsigned)f2bf(f[3]) << 16);
    v.z = f2bf(f[4]) | ((unsigned)f2bf(f[5]) << 16);
    v.w = f2bf(f[6]) | ((unsigned)f2bf(f[7]) << 16);
    return v;
}

// ---------------- CSR build ----------------
__global__ __launch_bounds__(256) void zero_ints(int* p, int n) {
    int i = blockIdx.x * 256 + threadIdx.x;
    if (i < n) p[i] = 0;
}

__global__ __launch_bounds__(256) void count_deg(const int* __restrict__ dst, int* __restrict__ deg) {
    int e = blockIdx.x * 256 + threadIdx.x;
    if (e < NEDGE) atomicAdd(&deg[dst[e]], 1);
}

__global__ __launch_bounds__(256) void scan_deg(const int* __restrict__ deg, int* __restrict__ row_ptr) {
    __shared__ int csum[256];
    int t = threadIdx.x;
    int loc[8];
    int s = 0;
#pragma unroll
    for (int q = 0; q < 8; q++) { loc[q] = s; s += deg[t * 8 + q]; }
    csum[t] = s;
    __syncthreads();
    for (int off = 1; off < 256; off <<= 1) {
        int v = (t >= off) ? csum[t - off] : 0;
        __syncthreads();
        csum[t] += v;
        __syncthreads();
    }
    int base = (t == 0) ? 0 : csum[t - 1];
#pragma unroll
    for (int q = 0; q < 8; q++) row_ptr[t * 8 + q] = base + loc[q];
    if (t == 255) row_ptr[2048] = csum[255];
}

__global__ __launch_bounds__(256) void fill_csr(const int* __restrict__ src, const int* __restrict__ dst,
                                                const int* __restrict__ row_ptr, int* __restrict__ cursor,
                                                int* __restrict__ col) {
    int e = blockIdx.x * 256 + threadIdx.x;
    if (e < NEDGE) {
        int d = dst[e];
        int pos = atomicAdd(&cursor[d], 1);
        col[row_ptr[d] + pos] = src[e];
    }
}

// ---------------- weight prep: transpose to [n][k], bf16 ----------------
// w1t: 4 regions of 16384; layer 0 uses [128 n][32 k] (k>=16 zero), layers 1-3 [128][128]
// w2t: 4 regions of 16384; layers 0-2 [128][128], layer 3 [64][128]
__global__ __launch_bounds__(256) void prep_weights(const float* __restrict__ W1f, const float* __restrict__ W1r,
                                                    const float* __restrict__ W2m, const float* __restrict__ W2l,
                                                    ushort_t* __restrict__ w1t, ushort_t* __restrict__ w2t) {
    int i = blockIdx.x * 256 + threadIdx.x;
    if (i < 65536) {
        int l = i >> 14, r = i & 16383;
        float v = 0.f;
        if (l == 0) {
            if (r < 4096) { int nn = r >> 5, k = r & 31; v = (k < 16) ? W1f[k * 128 + nn] : 0.f; }
        } else {
            int nn = r >> 7, k = r & 127;
            v = W1r[(size_t)(l - 1) * 16384 + k * 128 + nn];
        }
        w1t[i] = f2bf(v);
    } else {
        int j = i - 65536;
        int l = j >> 14, r = j & 16383;
        float v = 0.f;
        if (l < 3) {
            int nn = r >> 7, k = r & 127;
            v = W2m[(size_t)l * 16384 + k * 128 + nn];
        } else if (r < 8192) {
            int nn = r >> 7, k = r & 127;
            v = W2l[k * 64 + nn];
        }
        w2t[j] = f2bf(v);
    }
}

// A-layout for a 64x128 (or 64x32) bf16 tile: elem(m, k) at ((k>>3)*64 + m)*8 + (k&7)
// -> per-lane MFMA A-fragment (m=lane&15 [+16*mt], k=(lane>>4)*8+j) is 8 contiguous bf16.

// ---------------- fused gather + MFMA matmul1 + BN partial stats ----------------
template <int D_IN>
__global__ __launch_bounds__(256, 4) void gin_mm1(const void* __restrict__ Xv, const ushort_t* __restrict__ W1t,
                                                  const float* __restrict__ b1, const float* __restrict__ eps, int l,
                                                  const int* __restrict__ row_ptr, const int* __restrict__ col,
                                                  ushort_t* __restrict__ H, float* __restrict__ partial) {
    __shared__ ushort_t Zs[64 * 128];  // 16 KB
    int tid = threadIdx.x, n = blockIdx.x;
    float ev = 1.0f + eps[l];
    int e0 = row_ptr[n], e1 = row_ptr[n + 1];

    if (D_IN == 128) {
        const uint4* X = (const uint4*)Xv;  // bf16, A-layout slabs of 1024 uint4
        float acc[4][8];
#pragma unroll
        for (int q = 0; q < 4; q++) {
            uint4 v = X[(size_t)n * 1024 + q * 256 + tid];
            float f[8]; unpack8(v, f);
#pragma unroll
            for (int j = 0; j < 8; j++) acc[q][j] = f[j] * ev;
        }
        for (int e = e0; e < e1; e++) {
            const uint4* Xs = X + (size_t)col[e] * 1024;
#pragma unroll
            for (int q = 0; q < 4; q++) {
                uint4 v = Xs[q * 256 + tid];
                float f[8]; unpack8(v, f);
#pragma unroll
                for (int j = 0; j < 8; j++) acc[q][j] += f[j];
            }
        }
#pragma unroll
        for (int q = 0; q < 4; q++) ((uint4*)Zs)[q * 256 + tid] = pack8(acc[q]);
    } else {
        // layer 0: X is the original fp32 input [n][64 m][16 k]; pad K to 32 with zeros
        const float4* X = (const float4*)Xv;
        float4 a = X[(size_t)n * 256 + tid];
        a.x *= ev; a.y *= ev; a.z *= ev; a.w *= ev;
        for (int e = e0; e < e1; e++) {
            float4 v = X[(size_t)col[e] * 256 + tid];
            a.x += v.x; a.y += v.y; a.z += v.z; a.w += v.w;
        }
        int m = tid >> 2, k0 = (tid & 3) * 4;
        int addr = ((k0 >> 3) * 64 + m) * 8 + (k0 & 7);
        uint2 pv;
        pv.x = f2bf(a.x) | ((unsigned)f2bf(a.y) << 16);
        pv.y = f2bf(a.z) | ((unsigned)f2bf(a.w) << 16);
        *(uint2*)&Zs[addr] = pv;
        *(uint2*)&Zs[1024 + tid * 4] = make_uint2(0u, 0u);  // zero k=16..31
    }
    __syncthreads();

    constexpr int KB = (D_IN == 128) ? 4 : 1;
    constexpr int WS = (D_IN == 128) ? 128 : 32;  // W1t row stride (k extent)
    int w = tid >> 6, lane = tid & 63, lg = lane >> 4, ln = lane & 15;
    floatx4 C[4][2];
#pragma unroll
    for (int mt = 0; mt < 4; mt++) {
        C[mt][0] = {0.f, 0.f, 0.f, 0.f};
        C[mt][1] = {0.f, 0.f, 0.f, 0.f};
    }

    for (int kb = 0; kb < KB; kb++) {
        short8 B0 = *(const short8*)&W1t[(w * 32 + ln) * WS + kb * 32 + lg * 8];
        short8 B1 = *(const short8*)&W1t[(w * 32 + 16 + ln) * WS + kb * 32 + lg * 8];
#pragma unroll
        for (int mt = 0; mt < 4; mt++) {
            short8 A = *(const short8*)&Zs[((kb * 4 + lg) * 64 + mt * 16 + ln) * 8];
            C[mt][0] = __builtin_amdgcn_mfma_f32_16x16x32_bf16(A, B0, C[mt][0], 0, 0, 0);
            C[mt][1] = __builtin_amdgcn_mfma_f32_16x16x32_bf16(A, B1, C[mt][1], 0, 0, 0);
        }
    }

    // bias + per-feature partial stats (sum over all 64 rows via lane-group reduce)
    float bsum[2], bsq[2];
    float bv[2] = {b1[w * 32 + ln], b1[w * 32 + 16 + ln]};
#pragma unroll
    for (int nt = 0; nt < 2; nt++) {
        float s = 0.f, s2 = 0.f;
#pragma unroll
        for (int mt = 0; mt < 4; mt++)
#pragma unroll
            for (int r = 0; r < 4; r++) {
                float v = C[mt][nt][r] + bv[nt];
                C[mt][nt][r] = v;
                s += v; s2 += v * v;
            }
        bsum[nt] = s; bsq[nt] = s2;
    }
#pragma unroll
    for (int nt = 0; nt < 2; nt++) {
        bsum[nt] += __shfl_xor(bsum[nt], 16, 64);
        bsum[nt] += __shfl_xor(bsum[nt], 32, 64);
        bsq[nt] += __shfl_xor(bsq[nt], 16, 64);
        bsq[nt] += __shfl_xor(bsq[nt], 32, 64);
    }
    if (lg == 0) {
        int c0 = w * 32 + ln;
        partial[(size_t)n * 256 + c0] = bsum[0];
        partial[(size_t)n * 256 + c0 + 16] = bsum[1];
        partial[(size_t)n * 256 + 128 + c0] = bsq[0];
        partial[(size_t)n * 256 + 128 + c0 + 16] = bsq[1];
    }

    // C-layout -> A-layout bf16 via LDS, then coalesced global store of H
    __syncthreads();
#pragma unroll
    for (int nt = 0; nt < 2; nt++) {
        int colc = w * 32 + nt * 16 + ln;
        int base = (colc >> 3) * 512 + (colc & 7);
#pragma unroll
        for (int mt = 0; mt < 4; mt++)
#pragma unroll
            for (int r = 0; r < 4; r++) {
                int row = mt * 16 + lg * 4 + r;
                Zs[base + row * 8] = f2bf(C[mt][nt][r]);
            }
    }
    __syncthreads();
#pragma unroll
    for (int q = 0; q < 4; q++)
        ((uint4*)&H[(size_t)n * 8192])[q * 256 + tid] = ((const uint4*)Zs)[q * 256 + tid];
}

// ---------------- BN stats reduce -> per-feature scale/shift ----------------
__global__ __launch_bounds__(256) void bn_stats(const float* __restrict__ partial, const float* __restrict__ gamma,
                                                const float* __restrict__ beta, float* __restrict__ scsh) {
    __shared__ float rs[256], rs2[256];
    int c = blockIdx.x, t = threadIdx.x;
    float s = 0.f, s2 = 0.f;
    for (int b = t; b < 2048; b += 256) {
        s += partial[(size_t)b * 256 + c];
        s2 += partial[(size_t)b * 256 + HIDD + c];
    }
    rs[t] = s; rs2[t] = s2;
    __syncthreads();
    for (int off = 128; off > 0; off >>= 1) {
        if (t < off) { rs[t] += rs[t + off]; rs2[t] += rs2[t + off]; }
        __syncthreads();
    }
    if (t == 0) {
        float mean = rs[0] / (float)ROWS;
        float var = rs2[0] / (float)ROWS - mean * mean;
        float sc = gamma[c] * rsqrtf(var + 1e-5f);
        scsh[c] = sc;
        scsh[HIDD + c] = beta[c] - mean * sc;
    }
}

// ---------------- matmul2: relu(BN(H)) @ W2 + b2 ----------------
template <int D_OUT, bool LAST>
__global__ __launch_bounds__(256, 4) void gin_mm2(const ushort_t* __restrict__ H, const ushort_t* __restrict__ W2t,
                                                  const float* __restrict__ b2, const float* __restrict__ scsh,
                                                  const float* __restrict__ mask, float* __restrict__ outf,
                                                  ushort_t* __restrict__ outb) {
    __shared__ ushort_t Hs[64 * 128];
    int tid = threadIdx.x, n = blockIdx.x;

    // load H (A-layout bf16), apply BN scale/shift + ReLU elementwise, restage to LDS
#pragma unroll
    for (int q = 0; q < 4; q++) {
        int c = q * 256 + tid;   // uint4 chunk; elems 8c..8c+7; kg = c>>6; cols kg*8+j
        uint4 v = ((const uint4*)&H[(size_t)n * 8192])[c];
        float f[8]; unpack8(v, f);
        int cb = (c >> 6) * 8;
#pragma unroll
        for (int j = 0; j < 8; j++) {
            f[j] = fmaxf(fmaf(f[j], scsh[cb + j], scsh[128 + cb + j]), 0.f);
        }
        ((uint4*)Hs)[c] = pack8(f);
    }
    __syncthreads();

    int w = tid >> 6, lane = tid & 63, lg = lane >> 4, ln = lane & 15;
    constexpr int NT = (D_OUT == 128) ? 2 : 1;
    floatx4 C[4][NT];
#pragma unroll
    for (int mt = 0; mt < 4; mt++)
#pragma unroll
        for (int nt = 0; nt < NT; nt++) C[mt][nt] = {0.f, 0.f, 0.f, 0.f};

    for (int kb = 0; kb < 4; kb++) {
        short8 B[NT];
#pragma unroll
        for (int nt = 0; nt < NT; nt++)
            B[nt] = *(const short8*)&W2t[(w * 16 * NT + nt * 16 + ln) * 128 + kb * 32 + lg * 8];
#pragma unroll
        for (int mt = 0; mt < 4; mt++) {
            short8 A = *(const short8*)&Hs[((kb * 4 + lg) * 64 + mt * 16 + ln) * 8];
#pragma unroll
            for (int nt = 0; nt < NT; nt++)
                C[mt][nt] = __builtin_amdgcn_mfma_f32_16x16x32_bf16(A, B[nt], C[mt][nt], 0, 0, 0);
        }
    }

    if (LAST) {
        int colc = w * 16 + ln;
        float bb = b2[colc];
        float pe = 0.f;
#pragma unroll
        for (int mt = 0; mt < 4; mt++)
#pragma unroll
            for (int r = 0; r < 4; r++) {
                int row = mt * 16 + lg * 4 + r;
                pe += mask[n * 64 + row] * (C[mt][0][r] + bb);
            }
        pe += __shfl_xor(pe, 16, 64);
        pe += __shfl_xor(pe, 32, 64);
        if (lg == 0) outf[(size_t)n * 64 + colc] = pe;
    } else {
        __syncthreads();
#pragma unroll
        for (int nt = 0; nt < NT; nt++) {
            int colc = w * 32 + nt * 16 + ln;
            float bb = b2[colc];
            int base = (colc >> 3) * 512 + (colc & 7);
#pragma unroll
            for (int mt = 0; mt < 4; mt++)
#pragma unroll
                for (int r = 0; r < 4; r++) {
                    int row = mt * 16 + lg * 4 + r;
                    Hs[base + row * 8] = f2bf(C[mt][nt][r] + bb);
                }
        }
        __syncthreads();
#pragma unroll
        for (int q = 0; q < 4; q++)
            ((uint4*)&outb[(size_t)n * 8192])[q * 256 + tid] = ((const uint4*)Hs)[q * 256 + tid];
    }
}

// ---------------- host launch ----------------
extern "C" void kernel_launch(void* const* d_in, const int* in_sizes, int n_in, void* d_out, int out_size,
                              void* d_ws, size_t ws_size, hipStream_t stream) {
    const float* W    = (const float*)d_in[0];
    const float* mask = (const float*)d_in[1];
    const int* src    = (const int*)d_in[2];
    const int* dst    = (const int*)d_in[3];
    const float* eps  = (const float*)d_in[4];
    const float* W1f  = (const float*)d_in[5];
    const float* b1f  = (const float*)d_in[6];
    const float* W1r  = (const float*)d_in[7];
    const float* b1r  = (const float*)d_in[8];
    const float* gam  = (const float*)d_in[9];
    const float* bet  = (const float*)d_in[10];
    const float* W2m  = (const float*)d_in[11];
    const float* b2m  = (const float*)d_in[12];
    const float* W2l  = (const float*)d_in[13];
    const float* b2l  = (const float*)d_in[14];
    float* out = (float*)d_out;

    // workspace layout
    ushort_t* Xb  = (ushort_t*)d_ws;          // 16,777,216 ushort (bf16 X, A-layout)
    ushort_t* Hb  = Xb + 16777216;            // 16,777,216 ushort
    ushort_t* w1t = Hb + 16777216;            // 65,536
    ushort_t* w2t = w1t + 65536;              // 65,536
    float* partial = (float*)(w2t + 65536);   // 2048*256 fp32
    float* scsh    = partial + 2048 * 256;    // 256
    int* ideg      = (int*)(scsh + 256);      // 2048
    int* icur      = ideg + 2048;             // 2048
    int* irp       = icur + 2048;             // 2049
    int* icol      = irp + 2052;              // 16384

    zero_ints<<<16, 256, 0, stream>>>(ideg, 4096);
    count_deg<<<NEDGE / 256, 256, 0, stream>>>(dst, ideg);
    scan_deg<<<1, 256, 0, stream>>>(ideg, irp);
    fill_csr<<<NEDGE / 256, 256, 0, stream>>>(src, dst, irp, icur, icol);
    prep_weights<<<512, 256, 0, stream>>>(W1f, W1r, W2m, W2l, w1t, w2t);

    for (int l = 0; l < 4; l++) {
        if (l == 0)
            gin_mm1<16><<<N_SUM, 256, 0, stream>>>(W, w1t, b1f, eps, 0, irp, icol, Hb, partial);
        else
            gin_mm1<128><<<N_SUM, 256, 0, stream>>>(Xb, w1t + l * 16384, b1r + (size_t)(l - 1) * 128, eps, l,
                                                    irp, icol, Hb, partial);

        bn_stats<<<HIDD, 256, 0, stream>>>(partial, gam + l * HIDD, bet + l * HIDD, scsh);

        if (l < 3)
            gin_mm2<128, false><<<N_SUM, 256, 0, stream>>>(Hb, w2t + l * 16384, b2m + (size_t)l * HIDD, scsh,
                                                           nullptr, nullptr, Xb);
        else
            gin_mm2<64, true><<<N_SUM, 256, 0, stream>>>(Hb, w2t + 3 * 16384, b2l, scsh, mask, out, nullptr);
    }
}